// Round 3
// baseline (1238.365 us; speedup 1.0000x reference)
//
#include <hip/hip_runtime.h>

typedef _Float16 half_t;
typedef __attribute__((ext_vector_type(8))) _Float16 half8;
typedef __attribute__((ext_vector_type(4))) _Float16 half4v;
typedef __attribute__((ext_vector_type(4))) float f32x4;

#define MFMA16(a,b,c) __builtin_amdgcn_mfma_f32_16x16x32_f16((a),(b),(c),0,0,0)

__device__ __forceinline__ void gld_lds16(const half_t* g, half_t* l){
    __builtin_amdgcn_global_load_lds((__attribute__((address_space(1))) void*)(g),
                                     (__attribute__((address_space(3))) void*)(l), 16, 0, 0);
}

// ---------------- fp32 -> fp16 convert ----------------
__global__ __launch_bounds__(256) void cvt_k(const float* __restrict__ s, half_t* __restrict__ d, int n4){
    int i = blockIdx.x * 256 + threadIdx.x;
    if (i < n4){
        float4 v = ((const float4*)s)[i];
        half4v h = { (half_t)v.x, (half_t)v.y, (half_t)v.z, (half_t)v.w };
        ((half4v*)d)[i] = h;
    }
}

__global__ __launch_bounds__(256) void cvtw_k(const float* __restrict__ w0, const float* __restrict__ w1,
                                              const float* __restrict__ w2, const float* __restrict__ w3,
                                              half_t* __restrict__ dst){
    const float* srcs[4] = {w0, w1, w2, w3};
    const float* s = srcs[blockIdx.y];
    int i = blockIdx.x * 256 + threadIdx.x;
    float4 v = ((const float4*)s)[i];
    half4v h = { (half_t)v.x, (half_t)v.y, (half_t)v.z, (half_t)v.w };
    ((half4v*)(dst))[(size_t)blockIdx.y * 1048576 + i] = h;
}

// ---------------- 256x256x64 8-phase NT GEMM (T2+T3+T4+T5) ---------------- (frozen from R2)
#define VMWAIT_(n) asm volatile("s_waitcnt vmcnt(" #n ")" ::: "memory")
#define VMWAIT(n)  VMWAIT_(n)

#define STAGE8(hh) { \
    const int Tt2 = (hh) >> 2, jj2 = (hh) & 3; \
    half_t* db = smem + ((jj2 & 1) << 15) + ((Tt2 & 1) << 14) + ((jj2 >> 1) << 13); \
    const half_t* Gs = ((jj2 & 1) ? Bg : Ag) + Tt2*64 + ((jj2 >> 1) << 5); \
    gld_lds16(Gs + off0, db + d0); \
    gld_lds16(Gs + off1, db + d1); \
}

#define PHASE8(Tt, jj, hh, VMN) { \
    half_t* Ah = smem + (((Tt) & 1) << 14) + (((jj) >> 1) << 13); \
    half_t* Bh = Ah + 32768; \
    half8 af[4], bf[4]; \
    _Pragma("unroll") for (int x = 0; x < 4; x++) af[x] = *(const half8*)(Ah + (((jj)&1)*4 + x)*1024 + cA); \
    _Pragma("unroll") for (int y = 0; y < 4; y++) bf[y] = *(const half8*)(Bh + y*1024 + cB); \
    if ((hh) < 128) STAGE8(hh); \
    if ((jj) & 1) VMWAIT(VMN); \
    asm volatile("s_barrier" ::: "memory"); \
    __builtin_amdgcn_s_setprio(1); \
    _Pragma("unroll") for (int x = 0; x < 4; x++) \
      _Pragma("unroll") for (int y = 0; y < 4; y++) \
        acc[((jj)&1)*4 + x][y] = MFMA16(af[x], bf[y], acc[((jj)&1)*4 + x][y]); \
    __builtin_amdgcn_s_setprio(0); \
    __builtin_amdgcn_sched_barrier(0); \
    asm volatile("s_barrier" ::: "memory"); \
}

__global__ __launch_bounds__(512) void gemm8(const half_t* __restrict__ A, const half_t* __restrict__ B,
                                             half_t* __restrict__ Qw, half_t* __restrict__ Kw,
                                             half_t* __restrict__ Vt, float* __restrict__ Co, int kind){
    const int tid  = threadIdx.x;
    const int lane = tid & 63;
    const int w4   = lane >> 4;
    const int l15  = lane & 15;
    const int l7   = lane & 7;
    const int wav  = tid >> 6;
    const int wavM = wav >> 2;      // 0..1  (M half)
    const int wnq  = wav & 3;       // 0..3  (N quarter)

    const int nwg = gridDim.x;
    const int wg  = blockIdx.x;
    const int swz = (wg & 7) * (nwg >> 3) + (wg >> 3);
    const int bm  = swz & 31;       // M/256 = 32
    const int bn  = swz >> 5;

    __shared__ __align__(16) half_t smem[65536];   // 128 KiB

    const half_t* Ag = A + (size_t)bm * 256 * 2048;
    const half_t* Bg = B + (size_t)bn * 256 * 2048;

    const int p0  = tid >> 3, q0 = tid & 7, c0 = q0 ^ (p0 & 7);
    const int off0 = (p0 + ((c0 >> 2) << 7)) * 2048 + ((c0 & 3) << 3);
    const int off1 = off0 + 131072;                 // +64 rows * 2048
    const int d0  = tid * 8, d1 = d0 + 4096;

    const int cA = l15*64 + (((w4 | (wavM << 2)) ^ l7) << 3);
    const int cB = ((wnq & 1)*64 + l15)*64 + (((w4 | ((wnq >> 1) << 2)) ^ l7) << 3);

    f32x4 acc[8][4] = {};

#pragma unroll
    for (int h = 0; h < 6; h++) STAGE8(h);
    VMWAIT(4);
    asm volatile("s_barrier" ::: "memory");

    for (int it = 0; it < 15; it++){
        const int h0 = it*8 + 6;
        PHASE8(2*it,   0, h0,     6); PHASE8(2*it,   1, h0 + 1, 6);
        PHASE8(2*it,   2, h0 + 2, 6); PHASE8(2*it,   3, h0 + 3, 6);
        PHASE8(2*it+1, 0, h0 + 4, 6); PHASE8(2*it+1, 1, h0 + 5, 6);
        PHASE8(2*it+1, 2, h0 + 6, 6); PHASE8(2*it+1, 3, h0 + 7, 6);
    }
    PHASE8(30, 0, 126, 6); PHASE8(30, 1, 127, 6);
    PHASE8(30, 2, 128, 6); PHASE8(30, 3, 129, 2);
    PHASE8(31, 0, 130, 0); PHASE8(31, 1, 131, 0);
    PHASE8(31, 2, 132, 0); PHASE8(31, 3, 133, 0);

    const int mB = bm*256 + wavM*128 + w4*4;
    const int nB = bn*256 + wnq*64 + l15;

    if (kind == 0){
#pragma unroll
        for (int mi = 0; mi < 8; mi++)
#pragma unroll
            for (int ni = 0; ni < 4; ni++){
                int n  = nB + ni*16;
                int which = n >> 11;
                int nb = n & 2047;
                int m0 = mB + mi*16;
                if (which < 2){
                    half_t* dst = which ? Kw : Qw;
#pragma unroll
                    for (int r = 0; r < 4; r++){
                        int m = m0 + r;
                        dst[(((size_t)(m >> 11)*16 + (nb >> 7))*2048 + (m & 2047))*128 + (nb & 127)] = (half_t)acc[mi][ni][r];
                    }
                } else {
                    half4v hv = {(half_t)acc[mi][ni][0], (half_t)acc[mi][ni][1],
                                 (half_t)acc[mi][ni][2], (half_t)acc[mi][ni][3]};
                    *(half4v*)(Vt + (((size_t)(m0 >> 11)*16 + (nb >> 7))*128 + (nb & 127))*2048 + (m0 & 2047)) = hv;
                }
            }
    } else {
#pragma unroll
        for (int mi = 0; mi < 8; mi++)
#pragma unroll
            for (int ni = 0; ni < 4; ni++){
                int n  = nB + ni*16;
                int m0 = mB + mi*16;
#pragma unroll
                for (int r = 0; r < 4; r++)
                    Co[(size_t)(m0 + r)*2048 + n] = acc[mi][ni][r];
            }
    }
}

// ---------------- RoPE in-place on Q/K [b*16+h][s][128] ----------------
__global__ __launch_bounds__(256) void rope_k(half_t* __restrict__ Qw, half_t* __restrict__ Kw,
                                              const float* __restrict__ cs, const float* __restrict__ sn){
    int t  = blockIdx.x * 256 + threadIdx.x;
    int d  = t & 63;
    int s  = (t >> 6) & 2047;
    int bh = t >> 17;
    float c  = cs[s*64 + d];
    float si = sn[s*64 + d];
    size_t base = ((size_t)bh*2048 + s)*128 + d;
    float q1 = (float)Qw[base], q2 = (float)Qw[base+64];
    Qw[base]    = (half_t)(q1*c - q2*si);
    Qw[base+64] = (half_t)(q1*si + q2*c);
    float k1 = (float)Kw[base], k2 = (float)Kw[base+64];
    Kw[base]    = (half_t)(k1*c - k2*si);
    Kw[base+64] = (half_t)(k1*si + k2*c);
}

// ---------------- Flash attention, S^T formulation, T14 async-stage ----------------
// Q[bh][s][128], K[bh][s][128], Vt[bh][128][s] -> AO [b*2048+s][h*128+d]
// Staging: global->reg issued BEFORE compute of current tile, reg->LDS written after
// the post-compute barrier (hides K/V load latency under QK/softmax/PV).
// 1D grid, XCD-grouped: all 16 q-tiles of a head on one XCD (K/V L2-resident).
// Q fragments pre-scaled by 1/sqrt(128)*log2(e): softmax runs in scaled domain.
__global__ __launch_bounds__(256, 3) void attn_k(const half_t* __restrict__ Q, const half_t* __restrict__ K,
                                                 const half_t* __restrict__ Vt, half_t* __restrict__ AO){
    const int tid  = threadIdx.x;
    const int lane = tid & 63;
    const int w    = lane >> 4;
    const int l15  = lane & 15;
    const int l7   = lane & 7;
    const int wav  = tid >> 6;
    const int bid  = blockIdx.x;          // 1024
    const int qt   = (bid >> 3) & 15;     // 16 q-tiles of 128
    const int bh   = (bid & 7) * 8 + (bid >> 7);   // head: 8 heads per XCD group

    // Ks 16KB | Vs 16KB | Ps 4 x (32x72) 18KB. Ob overlays Ks+Vs after K loop.
    __shared__ __align__(16) half_t smem[8192 + 8192 + 4*2304];
    half_t* Ks = smem;
    half_t* Vs = smem + 8192;
    half_t* Ps = smem + 16384 + wav*2304;
    half_t* Ob = smem + wav*4096;

    const float SSC = 0.08838834764831845f * 1.4426950408889634f;  // 1/sqrt(128) * log2(e)

    const half_t* Qb = Q + ((size_t)bh*2048 + qt*128 + wav*32)*128;
    half8 aq[2][4];
#pragma unroll
    for (int qi = 0; qi < 2; qi++)
#pragma unroll
        for (int ks = 0; ks < 4; ks++){
            half8 t = *(const half8*)(Qb + (qi*16 + l15)*128 + ks*32 + w*8);
            aq[qi][ks] = t * (half_t)SSC;       // fold softmax scale into Q
        }

    // staging constants (same LDS layout as gld_lds version: linear dest, pre-swizzled src)
    int koff[4], voff[4], soff[4];
#pragma unroll
    for (int i = 0; i < 4; i++){
        int c = tid + i*256;
        int key = c >> 4, pk = c & 15;
        koff[i] = key*128 + ((pk ^ (key & 7)) << 3);
        int d = c >> 3, pv = c & 7;
        voff[i] = (d << 11) + ((pv ^ (d & 7)) << 3);
        soff[i] = c * 8;
    }

    const half_t* Kbase = K  + (size_t)bh*2048*128;
    const half_t* Vbase = Vt + (size_t)bh*128*2048;

    float4 kst[4], vst[4];
    // prologue: stage tile 0
#pragma unroll
    for (int i = 0; i < 4; i++) kst[i] = *(const float4*)(Kbase + koff[i]);
#pragma unroll
    for (int i = 0; i < 4; i++) vst[i] = *(const float4*)(Vbase + voff[i]);
#pragma unroll
    for (int i = 0; i < 4; i++) *(float4*)(Ks + soff[i]) = kst[i];
#pragma unroll
    for (int i = 0; i < 4; i++) *(float4*)(Vs + soff[i]) = vst[i];
    __syncthreads();

    f32x4 oacc[8][2] = {};
    float m_[2] = {-1e30f, -1e30f};
    float l_[2] = {0.0f, 0.0f};

    for (int kt = 0; kt < 32; kt++){
        // issue next tile's loads to regs (completes under this tile's compute)
        if (kt < 31){
            const half_t* Kb = Kbase + (kt + 1)*64*128;
            const half_t* Vb = Vbase + (kt + 1)*64;
#pragma unroll
            for (int i = 0; i < 4; i++) kst[i] = *(const float4*)(Kb + koff[i]);
#pragma unroll
            for (int i = 0; i < 4; i++) vst[i] = *(const float4*)(Vb + voff[i]);
        }
        __builtin_amdgcn_sched_barrier(0);   // pin load issue before compute

        // S^T = K @ Q^T : rows=key (4 tiles), cols=q (2 tiles)
        f32x4 sacc[4][2] = {};
#pragma unroll
        for (int ks = 0; ks < 4; ks++){
#pragma unroll
            for (int t = 0; t < 4; t++){
                half8 kf = *(const half8*)(Ks + (t*16 + l15)*128 + (((ks*4 + w) ^ l7) << 3));
                sacc[t][0] = MFMA16(kf, aq[0][ks], sacc[t][0]);
                sacc[t][1] = MFMA16(kf, aq[1][ks], sacc[t][1]);
            }
        }

        // online softmax per q-column (scaled domain); defer-max rescale (exact)
#pragma unroll
        for (int qi = 0; qi < 2; qi++){
            float mx = sacc[0][qi][0];
#pragma unroll
            for (int t = 0; t < 4; t++)
#pragma unroll
                for (int r = 0; r < 4; r++) mx = fmaxf(mx, sacc[t][qi][r]);
            mx = fmaxf(mx, __shfl_xor(mx, 16));
            mx = fmaxf(mx, __shfl_xor(mx, 32));
            unsigned long long upd = __ballot(mx > m_[qi]);
            if (upd){
                float mn    = fmaxf(m_[qi], mx);
                float alpha = exp2f(m_[qi] - mn);
                m_[qi] = mn;
                l_[qi] *= alpha;
#pragma unroll
                for (int t = 0; t < 8; t++)
#pragma unroll
                    for (int r = 0; r < 4; r++) oacc[t][qi][r] *= alpha;
            }
            float mq = m_[qi];
            float sum = 0.0f;
#pragma unroll
            for (int t = 0; t < 4; t++){
                float p0 = exp2f(sacc[t][qi][0] - mq);
                float p1 = exp2f(sacc[t][qi][1] - mq);
                float p2 = exp2f(sacc[t][qi][2] - mq);
                float p3 = exp2f(sacc[t][qi][3] - mq);
                sum += (p0 + p1) + (p2 + p3);
                half4v hv = {(half_t)p0, (half_t)p1, (half_t)p2, (half_t)p3};
                *(half4v*)(Ps + (qi*16 + l15)*72 + t*16 + w*4) = hv;
            }
            sum += __shfl_xor(sum, 16);
            sum += __shfl_xor(sum, 32);
            l_[qi] += sum;
        }

        // O^T += V^T @ P^T
#pragma unroll
        for (int c2 = 0; c2 < 2; c2++){
            half8 pf0 = *(const half8*)(Ps + l15*72        + c2*32 + w*8);
            half8 pf1 = *(const half8*)(Ps + (16 + l15)*72 + c2*32 + w*8);
#pragma unroll
            for (int t = 0; t < 8; t++){
                half8 vf = *(const half8*)(Vs + (t*16 + l15)*64 + (((c2*4 + w) ^ l7) << 3));
                oacc[t][0] = MFMA16(vf, pf0, oacc[t][0]);
                oacc[t][1] = MFMA16(vf, pf1, oacc[t][1]);
            }
        }

        // all waves done reading Ks/Vs -> overwrite with next tile
        __syncthreads();
        if (kt < 31){
#pragma unroll
            for (int i = 0; i < 4; i++) *(float4*)(Ks + soff[i]) = kst[i];
#pragma unroll
            for (int i = 0; i < 4; i++) *(float4*)(Vs + soff[i]) = vst[i];
        }
        __syncthreads();
    }

    // epilogue: transpose O^T -> O through LDS, coalesced global stores
    float inv[2] = {1.0f / l_[0], 1.0f / l_[1]};
#pragma unroll
    for (int t = 0; t < 8; t++)
#pragma unroll
        for (int qi = 0; qi < 2; qi++){
            int q  = qi*16 + l15;
            int c8 = t*2 + (w>>1);
            int pc = c8 ^ l7;
            half4v hv = {(half_t)(oacc[t][qi][0]*inv[qi]), (half_t)(oacc[t][qi][1]*inv[qi]),
                         (half_t)(oacc[t][qi][2]*inv[qi]), (half_t)(oacc[t][qi][3]*inv[qi])};
            *(half4v*)(Ob + q*128 + pc*8 + (w&1)*4) = hv;
        }
    const int b = bh >> 4, h = bh & 15;
#pragma unroll
    for (int it = 0; it < 8; it++){
        int q  = it*4 + w;
        half8 rd = *(const half8*)(Ob + q*128 + ((l15 ^ (q&7)) << 3));
        int s = qt*128 + wav*32 + q;
        *(half8*)(AO + ((size_t)(b*2048 + s))*2048 + h*128 + l15*8) = rd;
    }
}

extern "C" void kernel_launch(void* const* d_in, const int* in_sizes, int n_in,
                              void* d_out, int out_size, void* d_ws, size_t ws_size,
                              hipStream_t stream){
    const float* x  = (const float*)d_in[0];
    const float* cs = (const float*)d_in[1];
    const float* sn = (const float*)d_in[2];
    const float* Wq = (const float*)d_in[3];
    const float* Wk = (const float*)d_in[4];
    const float* Wv = (const float*)d_in[5];
    const float* Wo = (const float*)d_in[6];

    half_t* ws = (half_t*)d_ws;
    half_t* xh = ws;
    half_t* w4 = ws + (size_t)16777216;
    half_t* qw = ws + (size_t)33554432;
    half_t* kw = ws + (size_t)50331648;
    half_t* vt = ws + (size_t)67108864;
    half_t* ao = ws + (size_t)83886080;

    cvt_k<<<16384, 256, 0, stream>>>(x, xh, 4194304);
    cvtw_k<<<dim3(4096, 4), 256, 0, stream>>>(Wq, Wk, Wv, Wo, w4);

    gemm8<<<768, 512, 0, stream>>>(xh, w4, qw, kw, vt, nullptr, 0);
    rope_k<<<32768, 256, 0, stream>>>(qw, kw, cs, sn);
    attn_k<<<1024, 256, 0, stream>>>(qw, kw, vt, ao);
    gemm8<<<256, 512, 0, stream>>>(ao, w4 + 12582912, nullptr, nullptr, nullptr,
                                   (float*)d_out, 1);
}

// Round 4
// 685.760 us; speedup vs baseline: 1.8058x; 1.8058x over previous
//
#include <hip/hip_runtime.h>

typedef _Float16 half_t;
typedef __attribute__((ext_vector_type(8))) _Float16 half8;
typedef __attribute__((ext_vector_type(4))) _Float16 half4v;
typedef __attribute__((ext_vector_type(4))) float f32x4;

#define MFMA16(a,b,c) __builtin_amdgcn_mfma_f32_16x16x32_f16((a),(b),(c),0,0,0)

__device__ __forceinline__ void gld_lds16(const half_t* g, half_t* l){
    __builtin_amdgcn_global_load_lds((__attribute__((address_space(1))) void*)(g),
                                     (__attribute__((address_space(3))) void*)(l), 16, 0, 0);
}

// ---------------- fp32 -> fp16 convert ----------------
__global__ __launch_bounds__(256) void cvt_k(const float* __restrict__ s, half_t* __restrict__ d, int n4){
    int i = blockIdx.x * 256 + threadIdx.x;
    if (i < n4){
        float4 v = ((const float4*)s)[i];
        half4v h = { (half_t)v.x, (half_t)v.y, (half_t)v.z, (half_t)v.w };
        ((half4v*)d)[i] = h;
    }
}

__global__ __launch_bounds__(256) void cvtw_k(const float* __restrict__ w0, const float* __restrict__ w1,
                                              const float* __restrict__ w2, const float* __restrict__ w3,
                                              half_t* __restrict__ dst){
    const float* srcs[4] = {w0, w1, w2, w3};
    const float* s = srcs[blockIdx.y];
    int i = blockIdx.x * 256 + threadIdx.x;
    float4 v = ((const float4*)s)[i];
    half4v h = { (half_t)v.x, (half_t)v.y, (half_t)v.z, (half_t)v.w };
    ((half4v*)(dst))[(size_t)blockIdx.y * 1048576 + i] = h;
}

// ---------------- 256x256x64 8-phase NT GEMM (T2+T3+T4+T5) ---------------- (frozen from R2)
#define VMWAIT_(n) asm volatile("s_waitcnt vmcnt(" #n ")" ::: "memory")
#define VMWAIT(n)  VMWAIT_(n)

#define STAGE8(hh) { \
    const int Tt2 = (hh) >> 2, jj2 = (hh) & 3; \
    half_t* db = smem + ((jj2 & 1) << 15) + ((Tt2 & 1) << 14) + ((jj2 >> 1) << 13); \
    const half_t* Gs = ((jj2 & 1) ? Bg : Ag) + Tt2*64 + ((jj2 >> 1) << 5); \
    gld_lds16(Gs + off0, db + d0); \
    gld_lds16(Gs + off1, db + d1); \
}

#define PHASE8(Tt, jj, hh, VMN) { \
    half_t* Ah = smem + (((Tt) & 1) << 14) + (((jj) >> 1) << 13); \
    half_t* Bh = Ah + 32768; \
    half8 af[4], bf[4]; \
    _Pragma("unroll") for (int x = 0; x < 4; x++) af[x] = *(const half8*)(Ah + (((jj)&1)*4 + x)*1024 + cA); \
    _Pragma("unroll") for (int y = 0; y < 4; y++) bf[y] = *(const half8*)(Bh + y*1024 + cB); \
    if ((hh) < 128) STAGE8(hh); \
    if ((jj) & 1) VMWAIT(VMN); \
    asm volatile("s_barrier" ::: "memory"); \
    __builtin_amdgcn_s_setprio(1); \
    _Pragma("unroll") for (int x = 0; x < 4; x++) \
      _Pragma("unroll") for (int y = 0; y < 4; y++) \
        acc[((jj)&1)*4 + x][y] = MFMA16(af[x], bf[y], acc[((jj)&1)*4 + x][y]); \
    __builtin_amdgcn_s_setprio(0); \
    __builtin_amdgcn_sched_barrier(0); \
    asm volatile("s_barrier" ::: "memory"); \
}

__global__ __launch_bounds__(512) void gemm8(const half_t* __restrict__ A, const half_t* __restrict__ B,
                                             half_t* __restrict__ Qw, half_t* __restrict__ Kw,
                                             half_t* __restrict__ Vt, float* __restrict__ Co, int kind){
    const int tid  = threadIdx.x;
    const int lane = tid & 63;
    const int w4   = lane >> 4;
    const int l15  = lane & 15;
    const int l7   = lane & 7;
    const int wav  = tid >> 6;
    const int wavM = wav >> 2;      // 0..1  (M half)
    const int wnq  = wav & 3;       // 0..3  (N quarter)

    const int nwg = gridDim.x;
    const int wg  = blockIdx.x;
    const int swz = (wg & 7) * (nwg >> 3) + (wg >> 3);
    const int bm  = swz & 31;       // M/256 = 32
    const int bn  = swz >> 5;

    __shared__ __align__(16) half_t smem[65536];   // 128 KiB

    const half_t* Ag = A + (size_t)bm * 256 * 2048;
    const half_t* Bg = B + (size_t)bn * 256 * 2048;

    const int p0  = tid >> 3, q0 = tid & 7, c0 = q0 ^ (p0 & 7);
    const int off0 = (p0 + ((c0 >> 2) << 7)) * 2048 + ((c0 & 3) << 3);
    const int off1 = off0 + 131072;                 // +64 rows * 2048
    const int d0  = tid * 8, d1 = d0 + 4096;

    const int cA = l15*64 + (((w4 | (wavM << 2)) ^ l7) << 3);
    const int cB = ((wnq & 1)*64 + l15)*64 + (((w4 | ((wnq >> 1) << 2)) ^ l7) << 3);

    f32x4 acc[8][4] = {};

#pragma unroll
    for (int h = 0; h < 6; h++) STAGE8(h);
    VMWAIT(4);
    asm volatile("s_barrier" ::: "memory");

    for (int it = 0; it < 15; it++){
        const int h0 = it*8 + 6;
        PHASE8(2*it,   0, h0,     6); PHASE8(2*it,   1, h0 + 1, 6);
        PHASE8(2*it,   2, h0 + 2, 6); PHASE8(2*it,   3, h0 + 3, 6);
        PHASE8(2*it+1, 0, h0 + 4, 6); PHASE8(2*it+1, 1, h0 + 5, 6);
        PHASE8(2*it+1, 2, h0 + 6, 6); PHASE8(2*it+1, 3, h0 + 7, 6);
    }
    PHASE8(30, 0, 126, 6); PHASE8(30, 1, 127, 6);
    PHASE8(30, 2, 128, 6); PHASE8(30, 3, 129, 2);
    PHASE8(31, 0, 130, 0); PHASE8(31, 1, 131, 0);
    PHASE8(31, 2, 132, 0); PHASE8(31, 3, 133, 0);

    const int mB = bm*256 + wavM*128 + w4*4;
    const int nB = bn*256 + wnq*64 + l15;

    if (kind == 0){
#pragma unroll
        for (int mi = 0; mi < 8; mi++)
#pragma unroll
            for (int ni = 0; ni < 4; ni++){
                int n  = nB + ni*16;
                int which = n >> 11;
                int nb = n & 2047;
                int m0 = mB + mi*16;
                if (which < 2){
                    half_t* dst = which ? Kw : Qw;
#pragma unroll
                    for (int r = 0; r < 4; r++){
                        int m = m0 + r;
                        dst[(((size_t)(m >> 11)*16 + (nb >> 7))*2048 + (m & 2047))*128 + (nb & 127)] = (half_t)acc[mi][ni][r];
                    }
                } else {
                    half4v hv = {(half_t)acc[mi][ni][0], (half_t)acc[mi][ni][1],
                                 (half_t)acc[mi][ni][2], (half_t)acc[mi][ni][3]};
                    *(half4v*)(Vt + (((size_t)(m0 >> 11)*16 + (nb >> 7))*128 + (nb & 127))*2048 + (m0 & 2047)) = hv;
                }
            }
    } else {
#pragma unroll
        for (int mi = 0; mi < 8; mi++)
#pragma unroll
            for (int ni = 0; ni < 4; ni++){
                int n  = nB + ni*16;
                int m0 = mB + mi*16;
#pragma unroll
                for (int r = 0; r < 4; r++)
                    Co[(size_t)(m0 + r)*2048 + n] = acc[mi][ni][r];
            }
    }
}

// ---------------- RoPE in-place on Q/K [b*16+h][s][128] ----------------
__global__ __launch_bounds__(256) void rope_k(half_t* __restrict__ Qw, half_t* __restrict__ Kw,
                                              const float* __restrict__ cs, const float* __restrict__ sn){
    int t  = blockIdx.x * 256 + threadIdx.x;
    int d  = t & 63;
    int s  = (t >> 6) & 2047;
    int bh = t >> 17;
    float c  = cs[s*64 + d];
    float si = sn[s*64 + d];
    size_t base = ((size_t)bh*2048 + s)*128 + d;
    float q1 = (float)Qw[base], q2 = (float)Qw[base+64];
    Qw[base]    = (half_t)(q1*c - q2*si);
    Qw[base+64] = (half_t)(q1*si + q2*c);
    float k1 = (float)Kw[base], k2 = (float)Kw[base+64];
    Kw[base]    = (half_t)(k1*c - k2*si);
    Kw[base+64] = (half_t)(k1*si + k2*c);
}

// ---------------- Flash attention: LDS double-buffer + counted vmcnt (T3/T4) ----------------
// Q[bh][s][128], K[bh][s][128], Vt[bh][128][s] -> AO [b*2048+s][h*128+d]
// Staging stays global_load_lds (zero VGPR cost -- the R3 reg-staging spilled to scratch).
// Per iter kt: issue tile kt+1 into other LDS buffer (8 loads/thr); vmcnt(8) waits only
// for tile kt (issued one full iteration ago); raw s_barrier publishes it; compute;
// closing barrier frees the buffer staged two iterations later. Never vmcnt(0) mid-loop.
// LDS: Ks dbuf 32K | Vs dbuf 32K | Ps 16K (stride-64 chunk-XOR swizzle) = 80 KB -> 2 blk/CU.
__global__ __launch_bounds__(256, 2) void attn_k(const half_t* __restrict__ Q, const half_t* __restrict__ K,
                                                 const half_t* __restrict__ Vt, half_t* __restrict__ AO){
    const int tid  = threadIdx.x;
    const int lane = tid & 63;
    const int w    = lane >> 4;
    const int l15  = lane & 15;
    const int l7   = lane & 7;
    const int wav  = tid >> 6;
    const int bid  = blockIdx.x;          // 1024
    const int qt   = (bid >> 3) & 15;     // 16 q-tiles of 128
    const int bh   = (bid & 7) * 8 + (bid >> 7);   // 8 heads per XCD group

    __shared__ __align__(16) half_t smem[40960];   // 80 KiB
    // [0,16384): Ks dbuf; [16384,32768): Vs dbuf; [32768,40960): Ps (wav*2048)
    half_t* Ps = smem + 32768 + wav*2048;
    half_t* Ob = smem + wav*4096;          // epilogue overlay on Ks dbuf

    const float SSC = 0.08838834764831845f * 1.4426950408889634f;  // 1/sqrt(128) * log2(e)

    const half_t* Qb = Q + ((size_t)bh*2048 + qt*128 + wav*32)*128;
    half8 aq[2][4];
#pragma unroll
    for (int qi = 0; qi < 2; qi++)
#pragma unroll
        for (int ks = 0; ks < 4; ks++){
            half8 t = *(const half8*)(Qb + (qi*16 + l15)*128 + ks*32 + w*8);
            aq[qi][ks] = t * (half_t)SSC;       // fold softmax scale into Q
        }

    const half_t* Kbase = K  + (size_t)bh*2048*128;
    const half_t* Vbase = Vt + (size_t)bh*128*2048;

    // prologue: issue tile 0 into buffer 0 (no wait -- first loop iter waits)
#pragma unroll
    for (int i = 0; i < 4; i++){
        int c = tid + i*256;
        int key = c >> 4, pc = c & 15;
        gld_lds16(Kbase + key*128 + ((pc ^ (key & 7)) << 3), smem + c*8);
    }
#pragma unroll
    for (int i = 0; i < 4; i++){
        int c = tid + i*256;
        int d = c >> 3, pc = c & 7;
        gld_lds16(Vbase + (size_t)d*2048 + ((pc ^ (d & 7)) << 3), smem + 16384 + c*8);
    }

    f32x4 oacc[8][2] = {};
    float m_[2] = {-1e30f, -1e30f};
    float l_[2] = {0.0f, 0.0f};

    for (int kt = 0; kt < 32; kt++){
        half_t* kb = smem + ((kt & 1) << 13);
        half_t* vb = smem + 16384 + ((kt & 1) << 13);

        if (kt < 31){
            const half_t* Kb = Kbase + (size_t)(kt + 1)*8192;
            const half_t* Vb = Vbase + (kt + 1)*64;
            half_t* kn = smem + (((kt + 1) & 1) << 13);
            half_t* vn = smem + 16384 + (((kt + 1) & 1) << 13);
#pragma unroll
            for (int i = 0; i < 4; i++){
                int c = tid + i*256;
                int key = c >> 4, pc = c & 15;
                gld_lds16(Kb + key*128 + ((pc ^ (key & 7)) << 3), kn + c*8);
            }
#pragma unroll
            for (int i = 0; i < 4; i++){
                int c = tid + i*256;
                int d = c >> 3, pc = c & 7;
                gld_lds16(Vb + (size_t)d*2048 + ((pc ^ (d & 7)) << 3), vn + c*8);
            }
            VMWAIT(8);      // tile kt resident (its 8 loads are the oldest)
        } else {
            VMWAIT(0);      // last tile: drain
        }
        asm volatile("s_barrier" ::: "memory");

        // S^T = K @ Q^T : rows=key (4 tiles), cols=q (2 tiles)
        f32x4 sacc[4][2] = {};
#pragma unroll
        for (int ks = 0; ks < 4; ks++){
#pragma unroll
            for (int t = 0; t < 4; t++){
                half8 kf = *(const half8*)(kb + (t*16 + l15)*128 + (((ks*4 + w) ^ l7) << 3));
                sacc[t][0] = MFMA16(kf, aq[0][ks], sacc[t][0]);
                sacc[t][1] = MFMA16(kf, aq[1][ks], sacc[t][1]);
            }
        }

        // online softmax per q-column (scaled domain); defer-max rescale (exact)
#pragma unroll
        for (int qi = 0; qi < 2; qi++){
            float mx = sacc[0][qi][0];
#pragma unroll
            for (int t = 0; t < 4; t++)
#pragma unroll
                for (int r = 0; r < 4; r++) mx = fmaxf(mx, sacc[t][qi][r]);
            mx = fmaxf(mx, __shfl_xor(mx, 16));
            mx = fmaxf(mx, __shfl_xor(mx, 32));
            unsigned long long upd = __ballot(mx > m_[qi]);
            if (upd){
                float mn    = fmaxf(m_[qi], mx);
                float alpha = exp2f(m_[qi] - mn);
                m_[qi] = mn;
                l_[qi] *= alpha;
#pragma unroll
                for (int t = 0; t < 8; t++)
#pragma unroll
                    for (int r = 0; r < 4; r++) oacc[t][qi][r] *= alpha;
            }
            float mq = m_[qi];
            float sum = 0.0f;
#pragma unroll
            for (int t = 0; t < 4; t++){
                float p0 = exp2f(sacc[t][qi][0] - mq);
                float p1 = exp2f(sacc[t][qi][1] - mq);
                float p2 = exp2f(sacc[t][qi][2] - mq);
                float p3 = exp2f(sacc[t][qi][3] - mq);
                sum += (p0 + p1) + (p2 + p3);
                half4v hv = {(half_t)p0, (half_t)p1, (half_t)p2, (half_t)p3};
                // stride-64 chunk-XOR: row = qi*16+l15 (row&7 == l7), col8 = t*2+(w>>1)
                *(half4v*)(Ps + (qi*16 + l15)*64 + (((t*2 + (w >> 1)) ^ l7) << 3) + (w & 1)*4) = hv;
            }
            sum += __shfl_xor(sum, 16);
            sum += __shfl_xor(sum, 32);
            l_[qi] += sum;
        }

        // O^T += V^T @ P^T
#pragma unroll
        for (int c2 = 0; c2 < 2; c2++){
            half8 pf0 = *(const half8*)(Ps + l15*64        + (((c2*4 + w) ^ l7) << 3));
            half8 pf1 = *(const half8*)(Ps + (16 + l15)*64 + (((c2*4 + w) ^ l7) << 3));
#pragma unroll
            for (int t = 0; t < 8; t++){
                half8 vf = *(const half8*)(vb + (t*16 + l15)*64 + (((c2*4 + w) ^ l7) << 3));
                oacc[t][0] = MFMA16(vf, pf0, oacc[t][0]);
                oacc[t][1] = MFMA16(vf, pf1, oacc[t][1]);
            }
        }

        asm volatile("s_barrier" ::: "memory");   // frees kb/vb for restage at kt+2
    }

    // epilogue: transpose O^T -> O through LDS, coalesced global stores
    float inv[2] = {1.0f / l_[0], 1.0f / l_[1]};
#pragma unroll
    for (int t = 0; t < 8; t++)
#pragma unroll
        for (int qi = 0; qi < 2; qi++){
            int q  = qi*16 + l15;
            int c8 = t*2 + (w>>1);
            int pc = c8 ^ l7;
            half4v hv = {(half_t)(oacc[t][qi][0]*inv[qi]), (half_t)(oacc[t][qi][1]*inv[qi]),
                         (half_t)(oacc[t][qi][2]*inv[qi]), (half_t)(oacc[t][qi][3]*inv[qi])};
            *(half4v*)(Ob + q*128 + pc*8 + (w&1)*4) = hv;
        }
    const int b = bh >> 4, h = bh & 15;
#pragma unroll
    for (int it = 0; it < 8; it++){
        int q  = it*4 + w;
        half8 rd = *(const half8*)(Ob + q*128 + ((l15 ^ (q&7)) << 3));
        int s = qt*128 + wav*32 + q;
        *(half8*)(AO + ((size_t)(b*2048 + s))*2048 + h*128 + l15*8) = rd;
    }
}

extern "C" void kernel_launch(void* const* d_in, const int* in_sizes, int n_in,
                              void* d_out, int out_size, void* d_ws, size_t ws_size,
                              hipStream_t stream){
    const float* x  = (const float*)d_in[0];
    const float* cs = (const float*)d_in[1];
    const float* sn = (const float*)d_in[2];
    const float* Wq = (const float*)d_in[3];
    const float* Wk = (const float*)d_in[4];
    const float* Wv = (const float*)d_in[5];
    const float* Wo = (const float*)d_in[6];

    half_t* ws = (half_t*)d_ws;
    half_t* xh = ws;
    half_t* w4 = ws + (size_t)16777216;
    half_t* qw = ws + (size_t)33554432;
    half_t* kw = ws + (size_t)50331648;
    half_t* vt = ws + (size_t)67108864;
    half_t* ao = ws + (size_t)83886080;

    cvt_k<<<16384, 256, 0, stream>>>(x, xh, 4194304);
    cvtw_k<<<dim3(4096, 4), 256, 0, stream>>>(Wq, Wk, Wv, Wo, w4);

    gemm8<<<768, 512, 0, stream>>>(xh, w4, qw, kw, vt, nullptr, 0);
    rope_k<<<32768, 256, 0, stream>>>(qw, kw, cs, sn);
    attn_k<<<1024, 256, 0, stream>>>(qw, kw, vt, ao);
    gemm8<<<256, 512, 0, stream>>>(ao, w4 + 12582912, nullptr, nullptr, nullptr,
                                   (float*)d_out, 1);
}